// Round 1
// baseline (1116.220 us; speedup 1.0000x reference)
//
#include <hip/hip_runtime.h>

#define BB 32
#define TT 256
#define NN 128
#define DD 64

#define FMA4(acc, s, v) do { \
    acc.x = __builtin_fmaf((s), (v).x, acc.x); \
    acc.y = __builtin_fmaf((s), (v).y, acc.y); \
    acc.z = __builtin_fmaf((s), (v).z, acc.z); \
    acc.w = __builtin_fmaf((s), (v).w, acc.w); } while (0)

// ---------------------------------------------------------------- K1: build M and LI^T
__global__ __launch_bounds__(256) void k_build(const float* __restrict__ A,
                                               float* __restrict__ Mg,
                                               float* __restrict__ LIt) {
    __shared__ float degs[NN];
    const int b = blockIdx.x;
    const int tid = threadIdx.x;
    const float* Ab = A + b * NN * NN;
    if (tid < NN) {
        float s = 0.f;
        const float4* A4 = (const float4*)(Ab + tid * NN);
        #pragma unroll 4
        for (int j = 0; j < NN / 4; ++j) { float4 v = A4[j]; s += v.x + v.y + v.z + v.w; }
        degs[tid] = s;
    }
    __syncthreads();
    for (int flat = tid; flat < NN * NN; flat += 256) {
        int i = flat >> 7, j = flat & 127;
        float a = Ab[flat];
        float base = -a + ((i == j) ? degs[i] : 0.f);
        Mg[b * NN * NN + flat] = base + ((i == j) ? 1.1f : 0.f);
        LIt[b * NN * NN + j * NN + i] = base + ((i == j) ? 0.1f : 0.f);
    }
}

// ---------------------------------------------------------------- K2: in-place Gauss-Jordan inverse -> invM^T
__global__ __launch_bounds__(256) void k_invert(const float* __restrict__ Mg,
                                                float* __restrict__ invMt) {
    __shared__ float4 sM4s[NN * NN / 4];   // 64 KB
    float* sM = (float*)sM4s;
    float4* sM4 = sM4s;
    const int b = blockIdx.x;
    const int tid = threadIdx.x;
    for (int flat = tid; flat < NN * NN; flat += 256)
        sM[flat] = Mg[b * NN * NN + flat];
    __syncthreads();

    const int jq = tid & 31;      // float4 column index (j0 = 4*jq)
    const int rowoff = tid >> 5;  // 0..7
    const int jb = jq * 4;

    for (int k = 0; k < NN; ++k) {
        float p = 1.0f / sM[k * NN + k];   // read before any write this iter (prev iter ended in barrier)
        __syncthreads();
        if (tid < 32) {                    // scale row k; a[k][k] <- p
            float4 v = sM4[k * 32 + tid];
            int j0 = tid * 4;
            v.x = (j0 + 0 == k) ? p : v.x * p;
            v.y = (j0 + 1 == k) ? p : v.y * p;
            v.z = (j0 + 2 == k) ? p : v.z * p;
            v.w = (j0 + 3 == k) ? p : v.w * p;
            sM4[k * 32 + tid] = v;
        }
        __syncthreads();
        float4 akj = sM4[k * 32 + jq];     // scaled row k, hoisted
        #pragma unroll
        for (int p8 = 0; p8 < 16; ++p8) {
            int i = p8 * 8 + rowoff;       // wave-uniform row within half-wave group
            if (i == k) continue;
            float f = sM[i * NN + k];      // broadcast; read-before-write safe within lockstep half-wave
            float4 v = sM4[i * 32 + jq];
            v.x = ((jb + 0 == k) ? 0.f : v.x) - f * akj.x;
            v.y = ((jb + 1 == k) ? 0.f : v.y) - f * akj.y;
            v.z = ((jb + 2 == k) ? 0.f : v.z) - f * akj.z;
            v.w = ((jb + 3 == k) ? 0.f : v.w) - f * akj.w;
            sM4[i * 32 + jq] = v;
        }
        __syncthreads();
    }
    // write transposed: invMt[k][i] = invM[i][k]
    for (int flat = tid; flat < NN * NN; flat += 256) {
        int kk = flat >> 7, ii = flat & 127;
        invMt[b * NN * NN + flat] = sM[ii * NN + kk];
    }
}

// ---------------------------------------------------------------- K3: Wt[j][i] = sum_k invMt[k][i] * LIt[j][k]
__global__ __launch_bounds__(256) void k_wmat(const float* __restrict__ invMt,
                                              const float* __restrict__ LIt,
                                              float* __restrict__ Wt) {
    __shared__ float4 sLIt4s[16 * NN / 4];  // 8 KB: rows j = jg*16 .. +16
    float* sLIt = (float*)sLIt4s;
    const int bid = blockIdx.x;
    const int b = bid & 31, jg = bid >> 5;
    const int tid = threadIdx.x;
    const float4* LIt4 = (const float4*)(LIt + b * NN * NN + jg * 16 * NN);
    for (int q = tid; q < 512; q += 256) sLIt4s[q] = LIt4[q];
    __syncthreads();

    const int i4 = tid & 31;    // i0 = 4*i4
    const int jl0 = tid >> 5;   // 0..7 ; handles j-local jl0 and jl0+8
    const float4* inv4 = (const float4*)(invMt + b * NN * NN);
    float4 acc0 = {0, 0, 0, 0}, acc1 = {0, 0, 0, 0};
    #pragma unroll 4
    for (int k = 0; k < NN; ++k) {
        float4 m4 = inv4[k * 32 + i4];
        float l0 = sLIt[jl0 * NN + k];
        float l1 = sLIt[(jl0 + 8) * NN + k];
        FMA4(acc0, l0, m4);
        FMA4(acc1, l1, m4);
    }
    float4* Wt4 = (float4*)(Wt + b * NN * NN);
    int j0 = jg * 16 + jl0;
    Wt4[j0 * 32 + i4] = acc0;
    Wt4[(j0 + 8) * 32 + i4] = acc1;
}

// ---------------------------------------------------------------- K4: z[b,t] = invM @ x[b,t]  (written into d_out)
__global__ __launch_bounds__(256) void k_z(const float* __restrict__ invMt,
                                           const float* __restrict__ xs,
                                           float* __restrict__ out) {
    __shared__ float4 sInv4s[NN * NN / 4];  // 64 KB: invMt[k][i]
    __shared__ float4 sX4s[NN * DD / 4];    // 32 KB: x[k][d]
    float4* sInv4 = sInv4s;
    float4* sX4 = sX4s;
    const int bid = blockIdx.x;
    const int b = bid & 31, tc = bid >> 5;  // 8 t-chunks of 32
    const int tid = threadIdx.x;
    const float4* inv4 = (const float4*)(invMt + b * NN * NN);
    for (int q = tid; q < NN * NN / 4; q += 256) sInv4[q] = inv4[q];

    const float4* xs4 = (const float4*)(xs + (size_t)b * TT * NN * DD);
    float4* out4g = (float4*)(out + (size_t)b * TT * NN * DD);
    const int i4 = tid & 31;   // i0 = 4*i4
    const int dg = tid >> 5;   // d0 = 8*dg

    float4 xr[8];
    {
        int t = tc * 32;
        #pragma unroll
        for (int r = 0; r < 8; ++r) xr[r] = xs4[(size_t)t * (NN * DD / 4) + r * 256 + tid];
    }
    for (int tt = 0; tt < 32; ++tt) {
        int t = tc * 32 + tt;
        __syncthreads();                       // sX free (also covers sInv staging on first iter)
        #pragma unroll
        for (int r = 0; r < 8; ++r) sX4[r * 256 + tid] = xr[r];
        __syncthreads();
        if (tt < 31) {
            #pragma unroll
            for (int r = 0; r < 8; ++r) xr[r] = xs4[(size_t)(t + 1) * (NN * DD / 4) + r * 256 + tid];
        }
        float4 acc[4][2];
        #pragma unroll
        for (int r = 0; r < 4; ++r) { acc[r][0] = float4{0,0,0,0}; acc[r][1] = float4{0,0,0,0}; }
        #pragma unroll 2
        for (int k = 0; k < NN; ++k) {
            float4 m4 = sInv4[k * 32 + i4];
            float4 xa = sX4[k * 16 + dg * 2];
            float4 xb = sX4[k * 16 + dg * 2 + 1];
            FMA4(acc[0][0], m4.x, xa); FMA4(acc[0][1], m4.x, xb);
            FMA4(acc[1][0], m4.y, xa); FMA4(acc[1][1], m4.y, xb);
            FMA4(acc[2][0], m4.z, xa); FMA4(acc[2][1], m4.z, xb);
            FMA4(acc[3][0], m4.w, xa); FMA4(acc[3][1], m4.w, xb);
        }
        #pragma unroll
        for (int r = 0; r < 4; ++r) {
            out4g[(size_t)t * (NN * DD / 4) + (i4 * 4 + r) * 16 + dg * 2]     = acc[r][0];
            out4g[(size_t)t * (NN * DD / 4) + (i4 * 4 + r) * 16 + dg * 2 + 1] = acc[r][1];
        }
    }
}

// ---------------------------------------------------------------- K5: scan y_t = W y_{t-1} + z_t (in-place over z in d_out)
__global__ __launch_bounds__(256) void k_scan(const float* __restrict__ Wt,
                                              float* __restrict__ out) {
    __shared__ float4 yl4[NN * 8 / 4];        // y[j][8]   4 KB
    __shared__ float4 red4[4 * NN * 8 / 4];   // [w][i][8] 16 KB
    const int bid = blockIdx.x;
    const int b = bid & 31, dc = bid >> 5;    // dc 0..7 ; same-b blocks share an XCD
    const int tid = threadIdx.x;
    const int w = tid >> 6, q = tid & 63;

    // W in registers: thread holds W[i][j] for i in {2q,2q+1}, j in [32w,32w+32)
    float2 wv[32];
    const float2* Wt2 = (const float2*)(Wt + b * NN * NN + (w * 32) * NN);
    #pragma unroll
    for (int jj = 0; jj < 32; ++jj) wv[jj] = Wt2[jj * 64 + q];

    yl4[tid] = float4{0, 0, 0, 0};            // y0 = 0 (256 float4 = 1024 floats)
    float4* outbase4 = (float4*)(out + (size_t)b * TT * NN * DD);
    const int oi = tid >> 1, hf = tid & 1;
    float4 zp = outbase4[oi * 16 + dc * 2 + hf];   // prefetch z_0
    __syncthreads();

    for (int t = 0; t < TT; ++t) {
        float4 a00 = {0,0,0,0}, a01 = {0,0,0,0}, a10 = {0,0,0,0}, a11 = {0,0,0,0};
        #pragma unroll
        for (int jj = 0; jj < 32; ++jj) {
            int j = w * 32 + jj;
            float4 ya = yl4[j * 2];
            float4 yb = yl4[j * 2 + 1];
            float wa = wv[jj].x, wb = wv[jj].y;
            FMA4(a00, wa, ya); FMA4(a01, wa, yb);
            FMA4(a10, wb, ya); FMA4(a11, wb, yb);
        }
        __syncthreads();
        red4[w * 256 + q * 4 + 0] = a00;
        red4[w * 256 + q * 4 + 1] = a01;
        red4[w * 256 + q * 4 + 2] = a10;
        red4[w * 256 + q * 4 + 3] = a11;
        __syncthreads();
        float4 s0 = red4[      oi * 2 + hf];
        float4 s1 = red4[256 + oi * 2 + hf];
        float4 s2 = red4[512 + oi * 2 + hf];
        float4 s3 = red4[768 + oi * 2 + hf];
        float4 s;
        s.x = (s0.x + s1.x) + (s2.x + s3.x) + zp.x;
        s.y = (s0.y + s1.y) + (s2.y + s3.y) + zp.y;
        s.z = (s0.z + s1.z) + (s2.z + s3.z) + zp.z;
        s.w = (s0.w + s1.w) + (s2.w + s3.w) + zp.w;
        yl4[oi * 2 + hf] = s;
        outbase4[(size_t)t * (NN * DD / 4) + oi * 16 + dc * 2 + hf] = s;
        if (t + 1 < TT) zp = outbase4[(size_t)(t + 1) * (NN * DD / 4) + oi * 16 + dc * 2 + hf];
        __syncthreads();
    }
}

// ----------------------------------------------------------------
extern "C" void kernel_launch(void* const* d_in, const int* in_sizes, int n_in,
                              void* d_out, int out_size, void* d_ws, size_t ws_size,
                              hipStream_t stream) {
    const float* xs = (const float*)d_in[0];   // [32,256,128,64]
    const float* A  = (const float*)d_in[1];   // [32,128,128]
    float* out = (float*)d_out;                // [32,256,128,64]
    float* ws = (float*)d_ws;                  // needs 8 MB

    float* Mg    = ws;                          // [32][128][128]
    float* invMt = ws + 1 * BB * NN * NN;       // invM^T per batch
    float* LIt   = ws + 2 * BB * NN * NN;       // LI^T per batch
    float* Wtm   = ws + 3 * BB * NN * NN;       // W^T per batch

    k_build <<<BB, 256, 0, stream>>>(A, Mg, LIt);
    k_invert<<<BB, 256, 0, stream>>>(Mg, invMt);
    k_wmat  <<<256, 256, 0, stream>>>(invMt, LIt, Wtm);
    k_z     <<<256, 256, 0, stream>>>(invMt, xs, out);
    k_scan  <<<256, 256, 0, stream>>>(Wtm, out);
}